// Round 1
// baseline (1097.077 us; speedup 1.0000x reference)
//
#include <hip/hip_runtime.h>

#define NB   80
#define DIM  2048
#define CP   256
#define KH   5
#define HW   192      // 24*8
#define IDS  8
#define KC   1280     // KH*CP
#define DF   4096     // 2*DIM

// Generic 64x64 output tile fp32 GEMM: C[o0..o0+63][p0..p0+63] (+ activation)
// A: [M][KSIZE] row-major, B: [KSIZE][HW] row-major, C row stride = HW.
// 256 threads, 4x4 micro-tile per thread, K staged 16 at a time through LDS.
template<int KSIZE, int ACT>   // ACT: 0=none, 1=relu, 2=sigmoid
__device__ __forceinline__ void gemm_tile64(const float* __restrict__ A,
                                            const float* __restrict__ B,
                                            float* __restrict__ C,
                                            int o0, int p0)
{
    __shared__ float As[16][64];   // As[kk][oi]
    __shared__ float Bs[16][64];   // Bs[kk][pi]
    const int t  = threadIdx.x;
    const int ar = t >> 4;         // 0..15 -> row group
    const int ac = t & 15;         // 0..15 -> col group
    float acc[4][4] = {{0.f}};

    const int ia   = t * 4;
    const int a_oi = ia >> 4;      // 0..63
    const int a_kk = ia & 15;      // 0,4,8,12
    const int b_kk = ia >> 6;      // 0..15
    const int b_pi = ia & 63;      // 0,4,...,60

    for (int k0 = 0; k0 < KSIZE; k0 += 16) {
        float4 av = *reinterpret_cast<const float4*>(
            &A[(size_t)(o0 + a_oi) * KSIZE + k0 + a_kk]);
        float4 bv = *reinterpret_cast<const float4*>(
            &B[(size_t)(k0 + b_kk) * HW + p0 + b_pi]);
        As[a_kk + 0][a_oi] = av.x;
        As[a_kk + 1][a_oi] = av.y;
        As[a_kk + 2][a_oi] = av.z;
        As[a_kk + 3][a_oi] = av.w;
        *reinterpret_cast<float4*>(&Bs[b_kk][b_pi]) = bv;
        __syncthreads();
        #pragma unroll
        for (int kk = 0; kk < 16; ++kk) {
            float a[4], b[4];
            #pragma unroll
            for (int i = 0; i < 4; ++i) a[i] = As[kk][ar * 4 + i];
            #pragma unroll
            for (int j = 0; j < 4; ++j) b[j] = Bs[kk][ac * 4 + j];
            #pragma unroll
            for (int i = 0; i < 4; ++i)
                #pragma unroll
                for (int j = 0; j < 4; ++j)
                    acc[i][j] = fmaf(a[i], b[j], acc[i][j]);
        }
        __syncthreads();
    }
    #pragma unroll
    for (int i = 0; i < 4; ++i) {
        #pragma unroll
        for (int j = 0; j < 4; ++j) {
            float v = acc[i][j];
            if (ACT == 1) v = v > 0.f ? v : 0.f;
            if (ACT == 2) v = 1.f / (1.f + __expf(-v));
            C[(size_t)(o0 + ar * 4 + i) * HW + (p0 + ac * 4 + j)] = v;
        }
    }
}

// proj[n][o][p] = sum_c (sub[n] ? W_ri : W_rv)[o][c] * x[n][c][p]
__global__ __launch_bounds__(256) void proj_kernel(const float* __restrict__ x,
    const int* __restrict__ sub, const float* __restrict__ Wri,
    const float* __restrict__ Wrv, float* __restrict__ proj)
{
    const int n = blockIdx.z;
    const float* A = (sub[n] != 0) ? Wri : Wrv;
    const float* B = x + (size_t)n * DIM * HW;
    float* C = proj + (size_t)n * CP * HW;
    gemm_tile64<DIM, 0>(A, B, C, blockIdx.y * 64, blockIdx.x * 64);
}

// s[id][br][o][p] = relu( Wc[o][kk] * Aff ), Aff is the contiguous slice of proj
// covering the 5 same-id samples of that sub-branch (rows kk = j*256+o2 -> proj offset kk*HW).
__global__ __launch_bounds__(256) void compose_kernel(const float* __restrict__ proj,
    const float* __restrict__ Wci, const float* __restrict__ Wcv,
    float* __restrict__ sbuf)
{
    const int z  = blockIdx.z;
    const int br = z >> 3;     // 0 = branch i (sub==1), 1 = branch v (sub==0)
    const int id = z & 7;
    const float* A = (br == 0) ? Wci : Wcv;
    const float* B = proj + (size_t)(id * 10 + (br == 0 ? 0 : 5)) * CP * HW;
    float* C = sbuf + (size_t)(id * 2 + br) * DIM * HW;
    gemm_tile64<KC, 1>(A, B, C, blockIdx.y * 64, blockIdx.x * 64);
}

// fuse[id][o][p] = sigmoid( W_f[o][kk] * [s_i; s_v](id) ) — contiguous in sbuf.
__global__ __launch_bounds__(256) void fuse_kernel(const float* __restrict__ sbuf,
    const float* __restrict__ Wf, float* __restrict__ fusebuf)
{
    const int id = blockIdx.z;
    const float* B = sbuf + (size_t)id * DF * HW;
    float* C = fusebuf + (size_t)id * DIM * HW;
    gemm_tile64<DF, 2>(Wf, B, C, blockIdx.y * 64, blockIdx.x * 64);
}

// out[n][c][p] = x * (1 + fuse[labels[n]][c][p])
__global__ __launch_bounds__(256) void final_kernel(const float* __restrict__ x,
    const int* __restrict__ labels, const float* __restrict__ fusebuf,
    float* __restrict__ out)
{
    const size_t idx4 = (size_t)blockIdx.x * blockDim.x + threadIdx.x;
    const size_t e = idx4 * 4;
    const int n   = (int)(e / ((size_t)DIM * HW));
    const int rem = (int)(e % ((size_t)DIM * HW));
    const int id  = labels[n];
    float4 xv = *reinterpret_cast<const float4*>(x + e);
    float4 fv = *reinterpret_cast<const float4*>(fusebuf + (size_t)id * DIM * HW + rem);
    float4 o;
    o.x = xv.x + xv.x * fv.x;
    o.y = xv.y + xv.y * fv.y;
    o.z = xv.z + xv.z * fv.z;
    o.w = xv.w + xv.w * fv.w;
    *reinterpret_cast<float4*>(out + e) = o;
}

extern "C" void kernel_launch(void* const* d_in, const int* in_sizes, int n_in,
                              void* d_out, int out_size, void* d_ws, size_t ws_size,
                              hipStream_t stream) {
    const float* x      = (const float*)d_in[0];
    const int*   labels = (const int*)d_in[1];
    const int*   sub    = (const int*)d_in[2];
    const float* Wri    = (const float*)d_in[3];
    const float* Wrv    = (const float*)d_in[4];
    const float* Wci    = (const float*)d_in[5];
    const float* Wcv    = (const float*)d_in[6];
    const float* Wf     = (const float*)d_in[7];
    float* out = (float*)d_out;

    char* ws = (char*)d_ws;
    // Layout: [proj | sbuf]; fusebuf reuses proj's region (proj dead after compose).
    float* proj    = (float*)ws;                           // 80*256*192  = 15,728,640 B
    float* sbuf    = (float*)(ws + (size_t)15728640);      // 8*2*2048*192 = 25,165,824 B
    float* fusebuf = (float*)ws;                           // 8*2048*192  = 12,582,912 B (aliases proj)

    proj_kernel   <<<dim3(3,  4, NB),    256, 0, stream>>>(x, sub, Wri, Wrv, proj);
    compose_kernel<<<dim3(3, 32, 16),    256, 0, stream>>>(proj, Wci, Wcv, sbuf);
    fuse_kernel   <<<dim3(3, 32, IDS),   256, 0, stream>>>(sbuf, Wf, fusebuf);

    const int total4 = NB * DIM * HW / 4;   // 7,864,320
    final_kernel  <<<total4 / 256, 256, 0, stream>>>(x, labels, fusebuf, out);
}

// Round 2
// 451.601 us; speedup vs baseline: 2.4293x; 2.4293x over previous
//
#include <hip/hip_runtime.h>

typedef unsigned short u16;
typedef unsigned int u32;
typedef __bf16 bf16_t;
typedef bf16_t bf16x8 __attribute__((ext_vector_type(8)));
typedef float f32x4 __attribute__((ext_vector_type(4)));

#define DIM 2048
#define HW  192
#define CP  256
#define NB  80

__device__ __forceinline__ u16 f2b(float f) {
    u32 u = __float_as_uint(f);
    u32 r = (u + 0x7FFFu + ((u >> 16) & 1u)) >> 16;   // RNE
    return (u16)r;
}

__device__ __forceinline__ void g2l16(const void* g, void* l) {
    __builtin_amdgcn_global_load_lds(
        (const __attribute__((address_space(1))) u32*)g,
        (__attribute__((address_space(3))) u32*)l, 16, 0, 0);
}

// ---------------------------------------------------------------------------
// MFMA GEMM core. Block = 128 threads (2 waves). Output tile: 96 (n = act
// rows) x 128 (m = W rows). Wave w covers m-half w*64. Wave tile 96x64 =
// 6x4 MFMA tiles of 16x16, acc = 96 VGPRs/lane.
// act: [96 rows][K] bf16 k-major (row ptr per k-tile via functor, stride
// arstride). W: [128 rows][K] bf16, row stride wstride. Both staged to LDS
// via global_load_lds with XOR-chunk swizzle (chunk ^= (row>>1)&3).
// D layout (verified m89/m91): row(n) = quad*4+reg, col(m) = lane&15.
// ---------------------------------------------------------------------------
template<int ACT, bool OUTF32, typename F>   // ACT 0=none 1=relu
__device__ __forceinline__ void gemm_core(F actAddr, int arstride,
    const u16* __restrict__ Wp, int wstride, int K,
    void* __restrict__ outp, int M)
{
    __shared__ u16 act_s[96 * 32];
    __shared__ u16 w_s[128 * 32];
    const int t    = threadIdx.x;      // 0..127
    const int w    = t >> 6;           // wave id -> m half
    const int lane = t & 63;
    const int ln   = lane & 15;
    const int q    = lane >> 4;
    const int qe   = q ^ ((ln >> 1) & 3);   // de-swizzled chunk for frag reads

    f32x4 acc[6][4];
    #pragma unroll
    for (int i = 0; i < 6; ++i)
        #pragma unroll
        for (int j = 0; j < 4; ++j) acc[i][j] = (f32x4){0.f, 0.f, 0.f, 0.f};

    int a_off[6], b_off[4];
    #pragma unroll
    for (int i = 0; i < 6; ++i) a_off[i] = (i * 16 + ln) * 32 + qe * 8;
    #pragma unroll
    for (int j = 0; j < 4; ++j) b_off[j] = (w * 64 + j * 16 + ln) * 32 + qe * 8;

    for (int k0 = 0; k0 < K; k0 += 32) {
        const u16* ap = actAddr(k0);
        __syncthreads();   // prev iter's frag reads done before overwrite
        #pragma unroll
        for (int r = 0; r < 4; ++r) {            // W: 512 16B-slots
            int idx = r * 128 + t;
            int row = idx >> 2, pc = idx & 3;
            int lc  = pc ^ ((row >> 1) & 3);
            g2l16(Wp + (size_t)row * wstride + k0 + lc * 8, (void*)(w_s + idx * 8));
        }
        #pragma unroll
        for (int r = 0; r < 3; ++r) {            // act: 384 16B-slots
            int idx = r * 128 + t;
            int row = idx >> 2, pc = idx & 3;
            int lc  = pc ^ ((row >> 1) & 3);
            g2l16(ap + (size_t)row * arstride + lc * 8, (void*)(act_s + idx * 8));
        }
        __syncthreads();
        bf16x8 af[6], bf[4];
        #pragma unroll
        for (int i = 0; i < 6; ++i) af[i] = *(const bf16x8*)(act_s + a_off[i]);
        #pragma unroll
        for (int j = 0; j < 4; ++j) bf[j] = *(const bf16x8*)(w_s + b_off[j]);
        #pragma unroll
        for (int i = 0; i < 6; ++i)
            #pragma unroll
            for (int j = 0; j < 4; ++j)
                acc[i][j] = __builtin_amdgcn_mfma_f32_16x16x32_bf16(
                    af[i], bf[j], acc[i][j], 0, 0, 0);
    }
    #pragma unroll
    for (int i = 0; i < 6; ++i) {
        #pragma unroll
        for (int j = 0; j < 4; ++j) {
            #pragma unroll
            for (int r = 0; r < 4; ++r) {
                float v = acc[i][j][r];
                if (ACT == 1) v = v > 0.f ? v : 0.f;
                int nl = i * 16 + q * 4 + r;
                int ml = w * 64 + j * 16 + ln;
                if (OUTF32) ((float*)outp)[(size_t)nl * M + ml] = v;
                else        ((u16*)outp)[(size_t)nl * M + ml] = f2b(v);
            }
        }
    }
}

// proj: per sample n: projt[n][p][o] = sum_c x[n][c][p] * Wr_sel[o][c]
__global__ __launch_bounds__(128) void proj_g(const u16* __restrict__ xt,
    const int* __restrict__ sub, int nbase,
    const u16* __restrict__ Wri, const u16* __restrict__ Wrv,
    u16* __restrict__ projt)
{
    const int z = blockIdx.z, bn = blockIdx.x, bm = blockIdx.y;
    const int n = nbase + z;
    const u16* act = xt + (size_t)z * (HW * DIM) + (size_t)bn * 96 * DIM;
    const u16* Wp  = ((sub[n] != 0) ? Wri : Wrv) + (size_t)bm * 128 * DIM;
    u16* outp = projt + (size_t)n * (HW * CP) + (size_t)(bn * 96) * CP + bm * 128;
    auto f = [=](int k0) { return act + k0; };
    gemm_core<0, false>(f, DIM, Wp, DIM, DIM, outp, CP);
}

// compose: st[id][br][p][o] = relu( sum_kk projt[samp(j)][p][o2] * Wc[o][kk] )
__global__ __launch_bounds__(128) void compose_g(const u16* __restrict__ projt,
    const u16* __restrict__ Wci, const u16* __restrict__ Wcv,
    u16* __restrict__ st)
{
    const int z = blockIdx.z, br = z >> 3, id = z & 7;
    const int bn = blockIdx.x, bm = blockIdx.y;
    const u16* base = projt + (size_t)(id * 10 + br * 5) * (HW * CP) + (size_t)bn * 96 * CP;
    const u16* Wp   = (br ? Wcv : Wci) + (size_t)bm * 128 * 1280;
    u16* outp = st + (size_t)(id * 2 + br) * (HW * DIM) + (size_t)bn * 96 * DIM + bm * 128;
    auto f = [=](int k0) { return base + (size_t)(k0 >> 8) * (HW * CP) + (k0 & 255); };
    gemm_core<1, false>(f, CP, Wp, 1280, 1280, outp, DIM);
}

// fuse (K-split x2, raw partial sums fp32): fuset2[h][id][p][c]
__global__ __launch_bounds__(128) void fuse_g(const u16* __restrict__ st,
    const u16* __restrict__ Wf, float* __restrict__ fuset2)
{
    const int z = blockIdx.z, h = z >> 3, id = z & 7;
    const int bn = blockIdx.x, bm = blockIdx.y;
    const u16* base = st + (size_t)(id * 2 + h) * (HW * DIM) + (size_t)bn * 96 * DIM;
    const u16* Wp   = Wf + (size_t)bm * 128 * (2 * DIM) + (size_t)h * DIM;
    float* outp = fuset2 + (size_t)h * (8 * HW * DIM) + (size_t)id * (HW * DIM)
                + (size_t)bn * 96 * DIM + bm * 128;
    auto f = [=](int k0) { return base + k0; };
    gemm_core<0, true>(f, DIM, Wp, 2 * DIM, DIM, outp, DIM);
}

// x transpose-convert: xt[z][p][c] = bf16(x[z][c][p]); 64x64 tiles
__global__ __launch_bounds__(256) void xt_k(const float* __restrict__ x,
                                            u16* __restrict__ xt)
{
    __shared__ float ts[64][65];
    const int z = blockIdx.z;
    const int p0 = blockIdx.x * 64, c0 = blockIdx.y * 64;
    const int t = threadIdx.x, l = t & 63;
    #pragma unroll
    for (int i = 0; i < 16; ++i) {
        int cl = (t >> 6) * 16 + i;
        ts[cl][l] = x[((size_t)z * DIM + c0 + cl) * HW + p0 + l];
    }
    __syncthreads();
    #pragma unroll
    for (int i = 0; i < 16; ++i) {
        int pl = (t >> 6) * 16 + i;
        xt[((size_t)z * HW + p0 + pl) * DIM + c0 + l] = f2b(ts[l][pl]);
    }
}

// sum K-split halves, sigmoid, transpose: fuse[id][c][p]
__global__ __launch_bounds__(256) void fuse_tr(const float* __restrict__ fuset2,
                                               float* __restrict__ fuse)
{
    __shared__ float ts[64][65];
    const int id = blockIdx.z;
    const int c0 = blockIdx.x * 64, p0 = blockIdx.y * 64;
    const int t = threadIdx.x, l = t & 63;
    const float* f0 = fuset2;
    const float* f1 = fuset2 + (size_t)8 * HW * DIM;
    #pragma unroll
    for (int i = 0; i < 16; ++i) {
        int pl = (t >> 6) * 16 + i;
        size_t a = ((size_t)id * HW + p0 + pl) * DIM + c0 + l;
        float v = f0[a] + f1[a];
        ts[pl][l] = 1.f / (1.f + __expf(-v));
    }
    __syncthreads();
    #pragma unroll
    for (int i = 0; i < 16; ++i) {
        int cl = (t >> 6) * 16 + i;
        fuse[((size_t)id * DIM + c0 + cl) * HW + p0 + l] = ts[l][cl];
    }
}

// weights fp32 -> bf16 (all 5 concatenated logically)
__global__ __launch_bounds__(256) void wcvt(
    const float* __restrict__ a0, const float* __restrict__ a1,
    const float* __restrict__ a2, const float* __restrict__ a3,
    const float* __restrict__ a4,
    u16* __restrict__ o0, u16* __restrict__ o1, u16* __restrict__ o2,
    u16* __restrict__ o3, u16* __restrict__ o4)
{
    size_t off = ((size_t)blockIdx.x * 256 + threadIdx.x) * 4;
    const float* s; u16* d;
    if (off < 524288)            { s = a0; d = o0; }
    else if ((off -= 524288) < 524288)   { s = a1; d = o1; }
    else if ((off -= 524288) < 2621440)  { s = a2; d = o2; }
    else if ((off -= 2621440) < 2621440) { s = a3; d = o3; }
    else                         { off -= 2621440; s = a4; d = o4; }
    float4 v = *(const float4*)(s + off);
    ushort4 p;
    p.x = f2b(v.x); p.y = f2b(v.y); p.z = f2b(v.z); p.w = f2b(v.w);
    *(ushort4*)(d + off) = p;
}

// out[n][c][p] = x * (1 + fuse[labels[n]][c][p])
__global__ __launch_bounds__(256) void final_kernel(const float* __restrict__ x,
    const int* __restrict__ labels, const float* __restrict__ fusebuf,
    float* __restrict__ out)
{
    const size_t e = ((size_t)blockIdx.x * blockDim.x + threadIdx.x) * 4;
    const int n   = (int)(e / ((size_t)DIM * HW));
    const int rem = (int)(e % ((size_t)DIM * HW));
    const int id  = labels[n];
    float4 xv = *reinterpret_cast<const float4*>(x + e);
    float4 fv = *reinterpret_cast<const float4*>(fusebuf + (size_t)id * DIM * HW + rem);
    float4 o;
    o.x = xv.x + xv.x * fv.x;
    o.y = xv.y + xv.y * fv.y;
    o.z = xv.z + xv.z * fv.z;
    o.w = xv.w + xv.w * fv.w;
    *reinterpret_cast<float4*>(out + e) = o;
}

extern "C" void kernel_launch(void* const* d_in, const int* in_sizes, int n_in,
                              void* d_out, int out_size, void* d_ws, size_t ws_size,
                              hipStream_t stream) {
    const float* x      = (const float*)d_in[0];
    const int*   labels = (const int*)d_in[1];
    const int*   sub    = (const int*)d_in[2];
    const float* Wri    = (const float*)d_in[3];
    const float* Wrv    = (const float*)d_in[4];
    const float* Wci    = (const float*)d_in[5];
    const float* Wcv    = (const float*)d_in[6];
    const float* Wf     = (const float*)d_in[7];
    float* out = (float*)d_out;
    char* ws = (char*)d_ws;

    const bool full = ws_size >= (size_t)112721920;
    const size_t R1 = full ? (size_t)62914560 : (size_t)25165824;

    u16*   xtbuf  = (u16*)ws;                     // region R1 (xt, then fuset2)
    float* fuset2 = (float*)ws;                   // aliases xt (dead by then)
    char*  wreg   = ws + R1;
    u16* Wri_b = (u16*)(wreg);
    u16* Wrv_b = (u16*)(wreg + 1048576);
    u16* Wci_b = (u16*)(wreg + 2097152);
    u16* Wcv_b = (u16*)(wreg + 7340032);
    u16* Wf_b  = (u16*)(wreg + 12582912);
    float* fuse = (float*)(wreg + 12582912);      // aliases Wf_b (dead after fuse_g)
    u16* projt = (u16*)(wreg + 29360128);
    u16* stb   = (u16*)(wreg + 29360128 + 7864320);

    wcvt<<<14336, 256, 0, stream>>>(Wri, Wrv, Wci, Wcv, Wf,
                                    Wri_b, Wrv_b, Wci_b, Wcv_b, Wf_b);
    const int nchunk = full ? 1 : 4;
    const int cs = NB / nchunk;
    for (int c = 0; c < nchunk; ++c) {
        xt_k  <<<dim3(3, 32, cs), 256, 0, stream>>>(x + (size_t)c * cs * DIM * HW, xtbuf);
        proj_g<<<dim3(2, 2, cs), 128, 0, stream>>>(xtbuf, sub, c * cs, Wri_b, Wrv_b, projt);
    }
    compose_g<<<dim3(2, 16, 16), 128, 0, stream>>>(projt, Wci_b, Wcv_b, stb);
    fuse_g   <<<dim3(2, 16, 16), 128, 0, stream>>>(stb, Wf_b, fuset2);
    fuse_tr  <<<dim3(32, 3, 8), 256, 0, stream>>>(fuset2, fuse);
    final_kernel<<<30720, 256, 0, stream>>>(x, labels, fuse, out);
}

// Round 3
// 445.189 us; speedup vs baseline: 2.4643x; 1.0144x over previous
//
#include <hip/hip_runtime.h>

typedef unsigned short u16;
typedef unsigned int u32;
typedef __bf16 bf16_t;
typedef bf16_t bf16x8 __attribute__((ext_vector_type(8)));
typedef float f32x16 __attribute__((ext_vector_type(16)));

#define DIM 2048
#define HW  192
#define CP  256
#define NB  80

__device__ __forceinline__ u16 f2b(float f) {
    u32 u = __float_as_uint(f);
    u32 r = (u + 0x7FFFu + ((u >> 16) & 1u)) >> 16;   // RNE
    return (u16)r;
}

__device__ __forceinline__ void g2l16(const void* g, void* l) {
    __builtin_amdgcn_global_load_lds(
        (const __attribute__((address_space(1))) u32*)g,
        (__attribute__((address_space(3))) u32*)l, 16, 0, 0);
}

// ---------------------------------------------------------------------------
// MFMA GEMM core v2. Block = 128 threads (2 waves). Output tile 96(n)x128(m);
// wave w covers m-half w*64: 3x2 MFMA tiles of 32x32 (mfma_f32_32x32x16_bf16),
// acc = 96 VGPRs/lane. Double-buffered LDS (28 KB): stage k+1 overlaps MFMA k.
// act: [96][K] bf16 k-major (row ptr via functor, stride arstride).
// W: [128][K] bf16 row stride wstride. XOR-chunk swizzle (chunk ^= (row>>1)&3)
// breaks bank aliasing of the 64B rows forced by global_load_lds.
// A/B frag: row = lane&31, k = (lane>>5)*8 + e. D: col = lane&31,
// row = (r&3) + 8*(r>>2) + 4*(lane>>5)  [m74/m101].
// ---------------------------------------------------------------------------
template<int ACT, bool OUTF32, typename F>   // ACT 0=none 1=relu
__device__ __forceinline__ void gemm_core(F actAddr, int arstride,
    const u16* __restrict__ Wp, int wstride, int K,
    void* __restrict__ outp, int M)
{
    __shared__ u16 act_s[2][96 * 32];
    __shared__ u16 w_s[2][128 * 32];
    const int t    = threadIdx.x;      // 0..127
    const int w    = t >> 6;           // wave id -> m half
    const int lane = t & 63;
    const int ln   = lane & 31;
    const int q2   = lane >> 5;        // 0/1
    const int swz  = (ln >> 1) & 3;

    f32x16 acc[3][2];
    #pragma unroll
    for (int i = 0; i < 3; ++i)
        #pragma unroll
        for (int j = 0; j < 2; ++j)
            #pragma unroll
            for (int r = 0; r < 16; ++r) acc[i][j][r] = 0.f;

    auto stage = [&](int buf, int k0) {
        const u16* ap = actAddr(k0);
        #pragma unroll
        for (int r = 0; r < 4; ++r) {            // W: 512 16B slots
            int idx = r * 128 + t;
            int row = idx >> 2, pc = idx & 3;
            int lc  = pc ^ ((row >> 1) & 3);
            g2l16(Wp + (size_t)row * wstride + k0 + lc * 8, (void*)(w_s[buf] + idx * 8));
        }
        #pragma unroll
        for (int r = 0; r < 3; ++r) {            // act: 384 16B slots
            int idx = r * 128 + t;
            int row = idx >> 2, pc = idx & 3;
            int lc  = pc ^ ((row >> 1) & 3);
            g2l16(ap + (size_t)row * arstride + lc * 8, (void*)(act_s[buf] + idx * 8));
        }
    };

    auto compute = [&](int buf) {
        #pragma unroll
        for (int s = 0; s < 2; ++s) {            // two 16-k steps per 32-k tile
            bf16x8 af[3], bf[2];
            const int phys = (s * 2 + q2) ^ swz;
            #pragma unroll
            for (int i = 0; i < 3; ++i)
                af[i] = *(const bf16x8*)(act_s[buf] + (i * 32 + ln) * 32 + phys * 8);
            #pragma unroll
            for (int j = 0; j < 2; ++j)
                bf[j] = *(const bf16x8*)(w_s[buf] + (w * 64 + j * 32 + ln) * 32 + phys * 8);
            #pragma unroll
            for (int i = 0; i < 3; ++i)
                #pragma unroll
                for (int j = 0; j < 2; ++j)
                    acc[i][j] = __builtin_amdgcn_mfma_f32_32x32x16_bf16(
                        af[i], bf[j], acc[i][j], 0, 0, 0);
        }
    };

    stage(0, 0);
    const int iters = K / 32;
    for (int it = 0; it < iters; ++it) {
        int b = it & 1;
        __syncthreads();                // waits prev stage's g2l + frag reads
        if (it + 1 < iters) stage(b ^ 1, (it + 1) * 32);
        compute(b);
    }

    #pragma unroll
    for (int i = 0; i < 3; ++i) {
        #pragma unroll
        for (int j = 0; j < 2; ++j) {
            #pragma unroll
            for (int r = 0; r < 16; ++r) {
                float v = acc[i][j][r];
                if (ACT == 1) v = v > 0.f ? v : 0.f;
                int nl = i * 32 + (r & 3) + 8 * (r >> 2) + 4 * q2;
                int ml = w * 64 + j * 32 + ln;
                if (OUTF32) ((float*)outp)[(size_t)nl * M + ml] = v;
                else        ((u16*)outp)[(size_t)nl * M + ml] = f2b(v);
            }
        }
    }
}

// proj: projt[n][p][o] = sum_c x[n][c][p] * Wr_sel[o][c]
__global__ __launch_bounds__(128) void proj_g(const u16* __restrict__ xt,
    const int* __restrict__ sub, int nbase,
    const u16* __restrict__ Wri, const u16* __restrict__ Wrv,
    u16* __restrict__ projt)
{
    const int z = blockIdx.z, bn = blockIdx.x, bm = blockIdx.y;
    const int n = nbase + z;
    const u16* act = xt + (size_t)z * (HW * DIM) + (size_t)bn * 96 * DIM;
    const u16* Wp  = ((sub[n] != 0) ? Wri : Wrv) + (size_t)bm * 128 * DIM;
    u16* outp = projt + (size_t)n * (HW * CP) + (size_t)(bn * 96) * CP + bm * 128;
    auto f = [=](int k0) { return act + k0; };
    gemm_core<0, false>(f, DIM, Wp, DIM, DIM, outp, CP);
}

// compose: st[id][br][p][o] = relu( sum_kk projt[samp][p][o2] * Wc[o][kk] )
__global__ __launch_bounds__(128) void compose_g(const u16* __restrict__ projt,
    const u16* __restrict__ Wci, const u16* __restrict__ Wcv,
    u16* __restrict__ st)
{
    const int z = blockIdx.z, br = z >> 3, id = z & 7;
    const int bn = blockIdx.x, bm = blockIdx.y;
    const u16* base = projt + (size_t)(id * 10 + br * 5) * (HW * CP) + (size_t)bn * 96 * CP;
    const u16* Wp   = (br ? Wcv : Wci) + (size_t)bm * 128 * 1280;
    u16* outp = st + (size_t)(id * 2 + br) * (HW * DIM) + (size_t)bn * 96 * DIM + bm * 128;
    auto f = [=](int k0) { return base + (size_t)(k0 >> 8) * (HW * CP) + (k0 & 255); };
    gemm_core<1, false>(f, CP, Wp, 1280, 1280, outp, DIM);
}

// fuse, K-split x4 (h=0..3 covers k = h*1024 of [s_i;s_v]); fp32 partials.
__global__ __launch_bounds__(128) void fuse_g(const u16* __restrict__ st,
    const u16* __restrict__ Wf, float* __restrict__ fuset4)
{
    const int z = blockIdx.z, h = z >> 3, id = z & 7;
    const int bn = blockIdx.x, bm = blockIdx.y;
    const u16* base = st + (size_t)(id * 2 + (h >> 1)) * (HW * DIM)
                    + (size_t)bn * 96 * DIM + (h & 1) * 1024;
    const u16* Wp   = Wf + (size_t)bm * 128 * (2 * DIM) + (size_t)h * 1024;
    float* outp = fuset4 + (size_t)h * (8 * HW * DIM) + (size_t)id * (HW * DIM)
                + (size_t)bn * 96 * DIM + bm * 128;
    auto f = [=](int k0) { return base + k0; };
    gemm_core<0, true>(f, DIM, Wp, 2 * DIM, 1024, outp, DIM);
}

// x transpose-convert: xt[z][p][c] = bf16(x[z][c][p]); 64x64 tiles, float4 loads
__global__ __launch_bounds__(256) void xt_k(const float* __restrict__ x,
                                            u16* __restrict__ xt)
{
    __shared__ float ts[64][65];
    const int z = blockIdx.z;
    const int p0 = blockIdx.x * 64, c0 = blockIdx.y * 64;
    const int t = threadIdx.x;
    #pragma unroll
    for (int r = 0; r < 4; ++r) {
        int idx = r * 256 + t;
        int c = idx >> 4, p4 = (idx & 15) * 4;
        float4 v = *(const float4*)(x + ((size_t)z * DIM + c0 + c) * HW + p0 + p4);
        ts[c][p4 + 0] = v.x; ts[c][p4 + 1] = v.y;
        ts[c][p4 + 2] = v.z; ts[c][p4 + 3] = v.w;
    }
    __syncthreads();
    #pragma unroll
    for (int r = 0; r < 4; ++r) {
        int idx = r * 256 + t;
        int p = idx >> 4, c4 = (idx & 15) * 4;
        ushort4 o;
        o.x = f2b(ts[c4 + 0][p]); o.y = f2b(ts[c4 + 1][p]);
        o.z = f2b(ts[c4 + 2][p]); o.w = f2b(ts[c4 + 3][p]);
        *(ushort4*)(xt + ((size_t)z * HW + p0 + p) * DIM + c0 + c4) = o;
    }
}

// sum 4 K-split partials, sigmoid, transpose: fuse[id][c][p]
__global__ __launch_bounds__(256) void fuse_tr(const float* __restrict__ fuset4,
                                               float* __restrict__ fuse)
{
    __shared__ float ts[64][65];
    const int id = blockIdx.z;
    const int c0 = blockIdx.x * 64, p0 = blockIdx.y * 64;
    const int t = threadIdx.x, l = t & 63;
    const size_t hs = (size_t)8 * HW * DIM;
    #pragma unroll
    for (int i = 0; i < 16; ++i) {
        int pl = (t >> 6) * 16 + i;
        size_t a = ((size_t)id * HW + p0 + pl) * DIM + c0 + l;
        float v = fuset4[a] + fuset4[a + hs] + fuset4[a + 2 * hs] + fuset4[a + 3 * hs];
        ts[pl][l] = 1.f / (1.f + __expf(-v));
    }
    __syncthreads();
    #pragma unroll
    for (int i = 0; i < 16; ++i) {
        int cl = (t >> 6) * 16 + i;
        fuse[((size_t)id * DIM + c0 + cl) * HW + p0 + l] = ts[l][cl];
    }
}

// weights fp32 -> bf16
__global__ __launch_bounds__(256) void wcvt(
    const float* __restrict__ a0, const float* __restrict__ a1,
    const float* __restrict__ a2, const float* __restrict__ a3,
    const float* __restrict__ a4,
    u16* __restrict__ o0, u16* __restrict__ o1, u16* __restrict__ o2,
    u16* __restrict__ o3, u16* __restrict__ o4)
{
    size_t off = ((size_t)blockIdx.x * 256 + threadIdx.x) * 4;
    const float* s; u16* d;
    if (off < 524288)                    { s = a0; d = o0; }
    else if ((off -= 524288) < 524288)   { s = a1; d = o1; }
    else if ((off -= 524288) < 2621440)  { s = a2; d = o2; }
    else if ((off -= 2621440) < 2621440) { s = a3; d = o3; }
    else                                 { off -= 2621440; s = a4; d = o4; }
    float4 v = *(const float4*)(s + off);
    ushort4 p;
    p.x = f2b(v.x); p.y = f2b(v.y); p.z = f2b(v.z); p.w = f2b(v.w);
    *(ushort4*)(d + off) = p;
}

// out[n][c][p] = x * (1 + fuse[labels[n]][c][p])
__global__ __launch_bounds__(256) void final_kernel(const float* __restrict__ x,
    const int* __restrict__ labels, const float* __restrict__ fusebuf,
    float* __restrict__ out)
{
    const u32 e = ((u32)blockIdx.x * 256u + threadIdx.x) * 4u;
    const u32 n   = e / ((u32)DIM * HW);
    const u32 rem = e % ((u32)DIM * HW);
    const int id  = labels[n];
    float4 xv = *reinterpret_cast<const float4*>(x + e);
    float4 fv = *reinterpret_cast<const float4*>(fusebuf + (size_t)id * DIM * HW + rem);
    float4 o;
    o.x = xv.x + xv.x * fv.x;
    o.y = xv.y + xv.y * fv.y;
    o.z = xv.z + xv.z * fv.z;
    o.w = xv.w + xv.w * fv.w;
    *reinterpret_cast<float4*>(out + e) = o;
}

extern "C" void kernel_launch(void* const* d_in, const int* in_sizes, int n_in,
                              void* d_out, int out_size, void* d_ws, size_t ws_size,
                              hipStream_t stream) {
    const float* x      = (const float*)d_in[0];
    const int*   labels = (const int*)d_in[1];
    const int*   sub    = (const int*)d_in[2];
    const float* Wri    = (const float*)d_in[3];
    const float* Wrv    = (const float*)d_in[4];
    const float* Wci    = (const float*)d_in[5];
    const float* Wcv    = (const float*)d_in[6];
    const float* Wf     = (const float*)d_in[7];
    float* out = (float*)d_out;
    char* ws = (char*)d_ws;

    const bool full = ws_size >= (size_t)175636480;
    const size_t xtb = full ? (size_t)62914560 : (size_t)15728640;

    u16* Wri_b = (u16*)(ws);
    u16* Wrv_b = (u16*)(ws + 1048576);
    u16* Wci_b = (u16*)(ws + 2097152);
    u16* Wcv_b = (u16*)(ws + 7340032);
    u16* Wf_b  = (u16*)(ws + 12582912);
    u16* xtbuf = (u16*)(ws + 29360128);
    u16* projt = (u16*)(ws + 29360128 + xtb);
    u16* stb   = (u16*)(ws + 29360128 + xtb + 7864320);
    float* fuset4 = (float*)(ws + 29360128 + xtb + 7864320 + 12582912);
    float* fuse   = (float*)(ws + 29360128 + xtb + 7864320 + 12582912 + 50331648);

    wcvt<<<14336, 256, 0, stream>>>(Wri, Wrv, Wci, Wcv, Wf,
                                    Wri_b, Wrv_b, Wci_b, Wcv_b, Wf_b);
    const int nchunk = full ? 1 : 4;
    const int cs = NB / nchunk;
    for (int c = 0; c < nchunk; ++c) {
        xt_k  <<<dim3(3, 32, cs), 256, 0, stream>>>(x + (size_t)c * cs * DIM * HW, xtbuf);
        proj_g<<<dim3(2, 2, cs), 128, 0, stream>>>(xtbuf, sub, c * cs, Wri_b, Wrv_b, projt);
    }
    compose_g<<<dim3(2, 16, 16), 128, 0, stream>>>(projt, Wci_b, Wcv_b, stb);
    fuse_g   <<<dim3(2, 16, 32), 128, 0, stream>>>(stb, Wf_b, fuset4);
    fuse_tr  <<<dim3(32, 3, 8), 256, 0, stream>>>(fuset4, fuse);
    final_kernel<<<30720, 256, 0, stream>>>(x, labels, fuse, out);
}